// Round 8
// baseline (175.134 us; speedup 1.0000x reference)
//
#include <hip/hip_runtime.h>

// SDF volume rendering (NeuS/VolSDF-style), float32 in/out.
//
// Per ray (96 samples):
//   alpha_i = 1 - exp(-beta * sigmoid(-sdf_i * beta))
//   t_i     = 1 - alpha_i + 1e-10
//   trans_i = exclusive cumprod of t ;  w_i = alpha_i * trans_i
//   depth   = sum w_i * z_i ;  rgb_c = sum w_i * rgb_{i,c}
//
// R12: seven single-kernel structures (grids 2048-10240, VGPR 16-48, LDS /
// no-LDS, pipelined / not) all pin at 50-57us. R11 proved the compiler
// defeats any "all loads first" schedule (20 live dwordx3 needs >=60 VGPR,
// got 48). Model: we never reach steady-state MLP -- sustaining 6.3 TB/s
// needs ~22KB/CU continuously in flight; our waves issue one ~3.8KB pack,
// then go memory-silent for 1-2k cycles (exp/shfl/store), then die.
//
// Decisive split: TWO dispatches, each separately profiled.
//   K1 compute: proven 32-lane/ray scan, reads 126MB, writes 16B/ray ONLY.
//   K2 copy:    exact ubench shape (2048 blocks, grid-stride float4,
//               nt-stores) for the 50MB sdf/z passthrough. Runs after K1,
//               so K1's reads leave sdf/z L3-hot for K2.
// Whichever dispatch misses its roofline is the real wall (attribution!).

#define SDFR_NS 96

struct f3 { float x, y, z; };                              // 12B -> dwordx3
typedef float fv4 __attribute__((ext_vector_type(4)));     // true vector type

// ---------------------------------------------------------------- compute --
__global__ __launch_bounds__(256, 8) void sdf_compute_kernel(
    const float* __restrict__ rgb,      // [N*96*3]
    const float* __restrict__ sdf,      // [N*96]
    const float* __restrict__ z_vals,   // [N*96]
    const int*   __restrict__ beta_p,
    float* __restrict__ out_depth,      // [N]
    float* __restrict__ out_rgb,        // [N,3]
    int n_rays)
{
    const int tid = blockIdx.x * 256 + threadIdx.x;
    const int ray = tid >> 5;        // 2 rays per wave64
    const int l   = tid & 31;        // lane l owns samples [3l, 3l+3)
    if (ray >= n_rays) return;

    const int sb = ray * SDFR_NS + 3 * l;
    const int rb = ray * (SDFR_NS * 3) + 9 * l;

    // 5 independent, branch-free, coalesced wide loads
    const f3 sv = *(const f3*)(sdf    + sb);
    const f3 zv = *(const f3*)(z_vals + sb);
    const f3 ca = *(const f3*)(rgb + rb + 0);
    const f3 cb = *(const f3*)(rgb + rb + 3);
    const f3 cc = *(const f3*)(rgb + rb + 6);
    __builtin_amdgcn_sched_barrier(0);

    // beta decode: small int is the value; huge magnitude is an f32 pattern
    int bi = *beta_p;
    float beta;
    if (bi > 1000000 || bi < -1000000) {
        union { int i; float f; } u; u.i = bi; beta = u.f;
    } else {
        beta = (float)bi;
    }

    // sigmoid(-s*beta) = 1/(1+exp(s*beta)); e = exp(-beta*sig)
    const float e0 = __expf(-beta * __builtin_amdgcn_rcpf(1.0f + __expf(sv.x * beta)));
    const float e1 = __expf(-beta * __builtin_amdgcn_rcpf(1.0f + __expf(sv.y * beta)));
    const float e2 = __expf(-beta * __builtin_amdgcn_rcpf(1.0f + __expf(sv.z * beta)));
    const float a0 = 1.0f - e0, t0 = e0 + 1e-10f;
    const float a1 = 1.0f - e1, t1 = e1 + 1e-10f;
    const float a2 = 1.0f - e2, t2 = e2 + 1e-10f;

    // 32-lane exclusive prefix product of per-lane local product
    float scan = t0 * t1 * t2;
    #pragma unroll
    for (int d = 1; d < 32; d <<= 1) {
        float v = __shfl_up(scan, d, 32);
        if (l >= d) scan *= v;
    }
    float E = __shfl_up(scan, 1, 32);
    if (l == 0) E = 1.0f;

    const float w0 = a0 * E;
    const float w1 = a1 * E * t0;
    const float w2 = a2 * E * t0 * t1;

    float depth = w0 * zv.x + w1 * zv.y + w2 * zv.z;
    float r0    = w0 * ca.x + w1 * cb.x + w2 * cc.x;
    float r1    = w0 * ca.y + w1 * cb.y + w2 * cc.y;
    float r2    = w0 * ca.z + w1 * cb.z + w2 * cc.z;

    #pragma unroll
    for (int d = 16; d >= 1; d >>= 1) {
        depth += __shfl_xor(depth, d, 32);
        r0    += __shfl_xor(r0, d, 32);
        r1    += __shfl_xor(r1, d, 32);
        r2    += __shfl_xor(r2, d, 32);
    }

    // only stores: 16B per ray, at wave end
    if (l == 0) {
        out_depth[ray] = depth;
        f3 o; o.x = r0; o.y = r1; o.z = r2;
        *(f3*)(out_rgb + ray * 3) = o;
    }
}

// ------------------------------------------------------------------- copy --
#define SDFR_CPB 2048   // copy grid: 2048 blocks x 256 thr (ubench shape)

__global__ __launch_bounds__(256, 8) void sdf_copy_kernel(
    const float* __restrict__ sdf,
    const float* __restrict__ z_vals,
    float* __restrict__ out_sdf,
    float* __restrict__ out_z,
    int n_rays)
{
    const int n4     = (n_rays * SDFR_NS) / 4;   // 1,572,864 @ N=65536
    const int stride = SDFR_CPB * 256;           // 524,288 -> 3 iters
    const fv4* __restrict__ s4 = (const fv4*)sdf;
    const fv4* __restrict__ z4 = (const fv4*)z_vals;
    fv4* __restrict__ os4 = (fv4*)out_sdf;
    fv4* __restrict__ oz4 = (fv4*)out_z;

    for (int i = blockIdx.x * 256 + threadIdx.x; i < n4; i += stride) {
        const fv4 a = s4[i];
        const fv4 b = z4[i];
        __builtin_nontemporal_store(a, os4 + i);
        __builtin_nontemporal_store(b, oz4 + i);
    }
}

extern "C" void kernel_launch(void* const* d_in, const int* in_sizes, int n_in,
                              void* d_out, int out_size, void* d_ws, size_t ws_size,
                              hipStream_t stream) {
    (void)n_in; (void)d_ws; (void)ws_size; (void)out_size;

    const float* rgb    = (const float*)d_in[0];
    const float* sdf    = (const float*)d_in[1];
    const float* z      = (const float*)d_in[2];
    const int*   beta_p = (const int*)d_in[3];

    const int n_rays = in_sizes[1] / SDFR_NS;  // 65536

    // output layout (f32): depth[N] | rgb[N*3] | sdf[N*96] | z[N*96]
    float* out_depth = (float*)d_out;
    float* out_rgb   = out_depth + n_rays;
    float* out_sdf   = out_rgb   + (size_t)n_rays * 3;
    float* out_z     = out_sdf   + (size_t)n_rays * SDFR_NS;

    // K1 first: its sdf/z reads leave them L3-hot for K2's copy.
    const int comp_blocks = (n_rays * 32 + 255) / 256;   // 8192
    sdf_compute_kernel<<<comp_blocks, 256, 0, stream>>>(
        rgb, sdf, z, beta_p, out_depth, out_rgb, n_rays);

    sdf_copy_kernel<<<SDFR_CPB, 256, 0, stream>>>(
        sdf, z, out_sdf, out_z, n_rays);
}

// Round 9
// 168.777 us; speedup vs baseline: 1.0377x; 1.0377x over previous
//
#include <hip/hip_runtime.h>

// SDF volume rendering (NeuS/VolSDF-style), float32 in/out.
//
// Per ray (96 samples):
//   alpha_i = 1 - exp(-beta * sigmoid(-sdf_i * beta))
//   t_i     = 1 - alpha_i + 1e-10
//   trans_i = exclusive cumprod of t ;  w_i = alpha_i * trans_i
//   depth   = sum w_i * z_i ;  rgb_c = sum w_i * rgb_{i,c}
//
// R13: R12's two-dispatch split gave attribution: compute alone = 44.8us
// for a 126MB read (2.8 TB/s) while the harness fillBuffer hits 6.7 TB/s
// on the same chip -- the READ side is the wall, and VGPR_Count=12 proves
// why: five live dwordx3 results need >=15 VGPRs, so the allocator
// serialized the loads (reuse -> s_waitcnt between each). sched_barrier
// constrains the scheduler, NOT register reuse. Same invariant all session
// (R5: 16 VGPR, R11: 48 < 60 needed).
//
// Fix: empty-asm KEEP-ALIVE naming all 15 loaded floats ("+v" each) right
// after the load pack. Register reuse across the pack becomes impossible,
// so all 5 loads issue back-to-back with ONE vmcnt wait. One change vs R9
// (best = 50us): same combined role-split kernel (copy blocks [0,2048)
// stream sdf/z->out with nt-stores; compute blocks after, store-free until
// wave end).

#define SDFR_NS 96
#define SDFR_NCOPY 2048   // copy blocks (dispatched first)

struct f3 { float x, y, z; };                              // 12B -> dwordx3
typedef float fv4 __attribute__((ext_vector_type(4)));     // true vector type

__global__ __launch_bounds__(256, 8) void sdf_render_kernel(
    const float* __restrict__ rgb,      // [N*96*3]
    const float* __restrict__ sdf,      // [N*96]
    const float* __restrict__ z_vals,   // [N*96]
    const int*   __restrict__ beta_p,   // scalar (int32, or f32 bit pattern)
    float* __restrict__ out_depth,      // [N]
    float* __restrict__ out_rgb,        // [N,3]
    float* __restrict__ out_sdf,        // [N*96]
    float* __restrict__ out_z,          // [N*96]
    int n_rays)
{
    const int t = threadIdx.x;

    if (blockIdx.x < SDFR_NCOPY) {
        // ---------------- copy role: pure float4 stream ----------------
        const int n4     = (n_rays * SDFR_NS) / 4;   // 1,572,864 @ N=65536
        const int stride = SDFR_NCOPY * 256;
        const fv4* __restrict__ s4 = (const fv4*)sdf;
        const fv4* __restrict__ z4 = (const fv4*)z_vals;
        fv4* __restrict__ os4 = (fv4*)out_sdf;
        fv4* __restrict__ oz4 = (fv4*)out_z;

        for (int i = blockIdx.x * 256 + t; i < n4; i += stride) {
            const fv4 a = s4[i];
            const fv4 b = z4[i];
            __builtin_nontemporal_store(a, os4 + i);
            __builtin_nontemporal_store(b, oz4 + i);
        }
        return;
    }

    // ---------------- compute role: 32 lanes per ray ----------------
    const int cbid = blockIdx.x - SDFR_NCOPY;
    const int tid  = cbid * 256 + t;
    const int ray  = tid >> 5;        // 2 rays per wave
    const int l    = tid & 31;        // lane l owns samples [3l, 3l+3)
    if (ray >= n_rays) return;

    const int sb = ray * SDFR_NS + 3 * l;        // sdf/z float index
    const int rb = ray * (SDFR_NS * 3) + 9 * l;  // rgb float index

    // 5 independent, branch-free, coalesced wide loads
    f3 sv = *(const f3*)(sdf    + sb);
    f3 zv = *(const f3*)(z_vals + sb);
    f3 ca = *(const f3*)(rgb + rb + 0);
    f3 cb = *(const f3*)(rgb + rb + 3);
    f3 cc = *(const f3*)(rgb + rb + 6);

    // KEEP-ALIVE: all 15 result floats simultaneously live at this point.
    // Register reuse across the load pack is now impossible -> allocator
    // cannot serialize the loads; they issue back-to-back, one vmcnt wait.
    asm volatile("" :
        "+v"(sv.x), "+v"(sv.y), "+v"(sv.z),
        "+v"(zv.x), "+v"(zv.y), "+v"(zv.z),
        "+v"(ca.x), "+v"(ca.y), "+v"(ca.z),
        "+v"(cb.x), "+v"(cb.y), "+v"(cb.z),
        "+v"(cc.x), "+v"(cc.y), "+v"(cc.z));

    // beta decode: small int is the value; huge magnitude is an f32 pattern
    int bi = *beta_p;
    float beta;
    if (bi > 1000000 || bi < -1000000) {
        union { int i; float f; } u; u.i = bi; beta = u.f;
    } else {
        beta = (float)bi;
    }

    // sigmoid(-s*beta) = 1/(1+exp(s*beta)); e = exp(-beta*sig)
    const float e0 = __expf(-beta * __builtin_amdgcn_rcpf(1.0f + __expf(sv.x * beta)));
    const float e1 = __expf(-beta * __builtin_amdgcn_rcpf(1.0f + __expf(sv.y * beta)));
    const float e2 = __expf(-beta * __builtin_amdgcn_rcpf(1.0f + __expf(sv.z * beta)));
    const float a0 = 1.0f - e0, t0 = e0 + 1e-10f;
    const float a1 = 1.0f - e1, t1 = e1 + 1e-10f;
    const float a2 = 1.0f - e2, t2 = e2 + 1e-10f;

    // 32-lane exclusive prefix product of per-lane local product
    float scan = t0 * t1 * t2;
    #pragma unroll
    for (int d = 1; d < 32; d <<= 1) {
        float v = __shfl_up(scan, d, 32);
        if (l >= d) scan *= v;
    }
    float E = __shfl_up(scan, 1, 32);
    if (l == 0) E = 1.0f;

    const float w0 = a0 * E;
    const float w1 = a1 * E * t0;
    const float w2 = a2 * E * t0 * t1;

    float depth = w0 * zv.x + w1 * zv.y + w2 * zv.z;
    float r0    = w0 * ca.x + w1 * cb.x + w2 * cc.x;
    float r1    = w0 * ca.y + w1 * cb.y + w2 * cc.y;
    float r2    = w0 * ca.z + w1 * cb.z + w2 * cc.z;

    #pragma unroll
    for (int d = 16; d >= 1; d >>= 1) {
        depth += __shfl_xor(depth, d, 32);
        r0    += __shfl_xor(r0, d, 32);
        r1    += __shfl_xor(r1, d, 32);
        r2    += __shfl_xor(r2, d, 32);
    }

    // only stores in the compute role: 16B per ray, at wave end
    if (l == 0) {
        out_depth[ray] = depth;
        f3 o; o.x = r0; o.y = r1; o.z = r2;
        *(f3*)(out_rgb + ray * 3) = o;
    }
}

extern "C" void kernel_launch(void* const* d_in, const int* in_sizes, int n_in,
                              void* d_out, int out_size, void* d_ws, size_t ws_size,
                              hipStream_t stream) {
    (void)n_in; (void)d_ws; (void)ws_size; (void)out_size;

    const float* rgb    = (const float*)d_in[0];
    const float* sdf    = (const float*)d_in[1];
    const float* z      = (const float*)d_in[2];
    const int*   beta_p = (const int*)d_in[3];

    const int n_rays = in_sizes[1] / SDFR_NS;  // 65536

    // output layout (f32): depth[N] | rgb[N*3] | sdf[N*96] | z[N*96]
    float* out_depth = (float*)d_out;
    float* out_rgb   = out_depth + n_rays;
    float* out_sdf   = out_rgb   + (size_t)n_rays * 3;
    float* out_z     = out_sdf   + (size_t)n_rays * SDFR_NS;

    // copy blocks first, then 32-lanes-per-ray compute blocks
    const int comp_blocks = (n_rays * 32 + 255) / 256;   // 8192
    const int grid = SDFR_NCOPY + comp_blocks;           // 10240
    sdf_render_kernel<<<grid, 256, 0, stream>>>(
        rgb, sdf, z, beta_p, out_depth, out_rgb, out_sdf, out_z, n_rays);
}